// Round 5
// baseline (442.743 us; speedup 1.0000x reference)
//
#include <hip/hip_runtime.h>
#include <hip/hip_bf16.h>
#include <math.h>

#define NN   50000
#define EE   1600000
#define ETOT (EE + NN)
#define HID  128
#define INF_ 64
#define OUTF 64

// bucketed CSR build
#define NBK  1024   // buckets (contiguous dst ranges)
#define NPB  49     // nodes per bucket (1024*49 = 50176 >= NN)
#define CAP  3072   // per-bucket capacity; mean ~1617, 1.9x headroom
#define BBLK 128    // blocks for k_bucket v3
#define CHUNK ((ETOT + BBLK - 1) / BBLK)   // 12891 edges per block

__device__ __forceinline__ float gelu_tanh(float x) {
    float x3 = x * x * x;
    float u  = 0.7978845608028654f * (x + 0.044715f * x3);
    return 0.5f * x * (1.0f + tanhf(u));
}

// ---------------- CSR build (bucketed counting sort) ----------------

__global__ void k_zero(int* bcur) {
    int i = blockIdx.x * 256 + threadIdx.x;
    if (i < NBK) bcur[i] = 0;
}

// pass 1 v3: per-block LDS counting sort of a 12.9K-edge chunk, then coalesced
// run writes into per-bucket streams. One global range-reserve atomic per
// (block,bucket) = 128/address contention; tmp writes are rank-ordered runs.
__global__ __launch_bounds__(1024) void k_bucket(const int* __restrict__ ei,
                                                 int* bcur, int* __restrict__ tmp) {
    __shared__ unsigned sortedv[CHUNK];
    __shared__ int hist[NBK], gbase[NBK], loff[NBK], lcur[NBK];
    int t = threadIdx.x;
    int lo = blockIdx.x * CHUNK;
    int hi = min(lo + CHUNK, ETOT);
    int bsize = hi - lo;
    hist[t] = 0;
    __syncthreads();
    for (int i = lo + t; i < hi; i += 1024) {
        int d = (i < EE) ? ei[EE + i] : i - EE;
        atomicAdd(&hist[d / NPB], 1);
    }
    __syncthreads();
    {
        int c = hist[t];
        gbase[t] = (c > 0) ? atomicAdd(&bcur[t], c) : 0;
        loff[t] = c;                      // scan workspace
    }
    __syncthreads();
    for (int d = 1; d < NBK; d <<= 1) {   // inclusive scan
        int v = (t >= d) ? loff[t - d] : 0;
        __syncthreads();
        loff[t] += v;
        __syncthreads();
    }
    {
        int ex = loff[t] - hist[t];       // exclusive
        __syncthreads();
        loff[t] = ex;
        lcur[t] = ex;
    }
    __syncthreads();
    for (int i = lo + t; i < hi; i += 1024) {
        unsigned s, d;
        if (i < EE) { s = (unsigned)ei[i]; d = (unsigned)ei[EE + i]; }
        else        { s = d = (unsigned)(i - EE); }
        unsigned b = d / NPB;
        int p = atomicAdd(&lcur[b], 1);
        sortedv[p] = (b << 22) | (s << 6) | (d - b * NPB);
    }
    __syncthreads();
    for (int i = t; i < bsize; i += 1024) {
        unsigned v = sortedv[i];
        unsigned b = v >> 22;
        int pp = gbase[b] + i - loff[b];   // local rank within bucket run
        if (pp < CAP) tmp[b * CAP + pp] = (int)(v & 0x3FFFFFu);
    }
}

// exclusive scan of 1024 bucket sizes (one block)
__global__ __launch_bounds__(1024) void k_bscan(const int* __restrict__ bcur,
                                                int* __restrict__ bstart,
                                                int* __restrict__ off) {
    __shared__ int s[NBK];
    int t = threadIdx.x;
    int v0 = bcur[t];
    s[t] = v0;
    __syncthreads();
    for (int d = 1; d < NBK; d <<= 1) {
        int v = (t >= d) ? s[t - d] : 0;
        __syncthreads();
        s[t] += v;
        __syncthreads();
    }
    bstart[t] = s[t] - v0;     // exclusive
    if (t == 0) off[NN] = ETOT;
}

// pass 2: one block per bucket — stage in LDS, count, scan, scatter; also emits
// per-edge dst id (dstid) for the edge-parallel weight kernel.
__global__ __launch_bounds__(256) void k_bucket2csr(const int* __restrict__ tmp,
                                                    const int* __restrict__ bcur,
                                                    const int* __restrict__ bstart,
                                                    int* __restrict__ off,
                                                    int* __restrict__ csr,
                                                    int* __restrict__ dstid) {
    __shared__ int sE[CAP];
    __shared__ int lcnt[NPB];
    __shared__ int loff[NPB];
    int b = blockIdx.x, t = threadIdx.x;
    int n0    = b * NPB;
    int bsize = min(bcur[b], CAP);
    int base  = bstart[b];
    if (t < NPB) lcnt[t] = 0;
    for (int i = t; i < bsize; i += 256) sE[i] = tmp[b * CAP + i];
    __syncthreads();
    for (int i = t; i < bsize; i += 256) atomicAdd(&lcnt[sE[i] & 63], 1);
    __syncthreads();
    if (t == 0) {
        int run = 0;
        for (int j = 0; j < NPB; ++j) { loff[j] = run; run += lcnt[j]; }
    }
    __syncthreads();
    if (t < NPB) {
        if (n0 + t < NN) off[n0 + t] = base + loff[t];
        lcnt[t] = loff[t];            // reuse as cursor
    }
    __syncthreads();
    for (int i = t; i < bsize; i += 256) {
        int v   = sE[i];
        int d   = v & 63;
        int pos = base + atomicAdd(&lcnt[d], 1);
        csr[pos]   = v >> 6;
        dstid[pos] = n0 + d;
    }
}

// ------- fused input-linear + LN + GELU + hW GEMM + head scores (16 nodes/block) -------

__global__ __launch_bounds__(128) void k_infeat(const float* __restrict__ x,
                                                const float* __restrict__ win,
                                                const float* __restrict__ bin,
                                                const float* __restrict__ g,
                                                const float* __restrict__ be,
                                                const float* __restrict__ W,
                                                const float* __restrict__ asrc,
                                                const float* __restrict__ adst,
                                                __hip_bfloat16* __restrict__ hWb,
                                                float* __restrict__ esrc,
                                                float* __restrict__ edst) {
    __shared__ __align__(16) float xr[16][INF_];
    __shared__ __align__(16) float hrow[16][HID + 4];   // +4 pad: LN bank spread
    int n0 = blockIdx.x * 16, t = threadIdx.x;
    for (int i = t; i < 16 * INF_; i += 128) xr[i >> 6][i & 63] = x[n0 * INF_ + i];
    __syncthreads();

    // GEMM1: h = x @ w_in + b_in, col t, 16 nodes
    {
        float acc[16];
        float bb = bin[t];
        #pragma unroll
        for (int r = 0; r < 16; ++r) acc[r] = bb;
        const float4* x4 = reinterpret_cast<const float4*>(&xr[0][0]);
        for (int k4 = 0; k4 < INF_ / 4; ++k4) {
            int k = k4 * 4;
            float w0 = win[(k + 0) * HID + t];
            float w1 = win[(k + 1) * HID + t];
            float w2 = win[(k + 2) * HID + t];
            float w3 = win[(k + 3) * HID + t];
            #pragma unroll
            for (int r = 0; r < 16; ++r) {
                float4 hv = x4[r * (INF_ / 4) + k4];
                acc[r] = fmaf(hv.x, w0, fmaf(hv.y, w1, fmaf(hv.z, w2, fmaf(hv.w, w3, acc[r]))));
            }
        }
        #pragma unroll
        for (int r = 0; r < 16; ++r) hrow[r][t] = acc[r];
    }
    __syncthreads();

    // LN + GELU: node = t>>3 (16 nodes), lane = t&7, 16 cols/lane, width-8 shuffles
    {
        int node = t >> 3, lane = t & 7;
        float s1 = 0.f, s2 = 0.f;
        #pragma unroll
        for (int j = 0; j < 16; ++j) {
            float v = hrow[node][lane + 8 * j];
            s1 += v; s2 += v * v;
        }
        #pragma unroll
        for (int m = 1; m < 8; m <<= 1) {
            s1 += __shfl_xor(s1, m, 8);
            s2 += __shfl_xor(s2, m, 8);
        }
        float mu  = s1 * (1.0f / 128.0f);
        float var = s2 * (1.0f / 128.0f) - mu * mu;
        float rs  = rsqrtf(var + 1e-5f);
        #pragma unroll
        for (int j = 0; j < 16; ++j) {
            int col = lane + 8 * j;
            float v = hrow[node][col];
            float y = (v - mu) * rs * g[col] + be[col];
            hrow[node][col] = gelu_tanh(y);
        }
    }
    __syncthreads();

    // GEMM2: hW = h @ W, col t, 16 nodes; + scores
    float acc[16];
    #pragma unroll
    for (int r = 0; r < 16; ++r) acc[r] = 0.f;
    const float4* h4 = reinterpret_cast<const float4*>(&hrow[0][0]);
    for (int k4 = 0; k4 < HID / 4; ++k4) {
        int k = k4 * 4;
        float w0 = W[(k + 0) * HID + t];
        float w1 = W[(k + 1) * HID + t];
        float w2 = W[(k + 2) * HID + t];
        float w3 = W[(k + 3) * HID + t];
        #pragma unroll
        for (int r = 0; r < 16; ++r) {
            float4 hv = h4[r * ((HID + 4) / 4) + k4];
            acc[r] = fmaf(hv.x, w0, fmaf(hv.y, w1, fmaf(hv.z, w2, fmaf(hv.w, w3, acc[r]))));
        }
    }
    float as = asrc[t], ad = adst[t];
    #pragma unroll
    for (int r = 0; r < 16; ++r) {
        hWb[(n0 + r) * HID + t] = __float2bfloat16(acc[r]);
        float v1 = acc[r] * as, v2 = acc[r] * ad;
        #pragma unroll
        for (int m = 1; m < 32; m <<= 1) {
            v1 += __shfl_xor(v1, m, 32);
            v2 += __shfl_xor(v2, m, 32);
        }
        if ((t & 31) == 0) {
            esrc[(n0 + r) * 4 + (t >> 5)] = v1;
            edst[(n0 + r) * 4 + (t >> 5)] = v2;
        }
    }
}

// ------- layer-2 feat: LN + GELU + hW GEMM + scores (16 nodes/block) -------

__global__ __launch_bounds__(128) void k_feat(const float* __restrict__ hin,
                                              const float* __restrict__ g,
                                              const float* __restrict__ be,
                                              const float* __restrict__ W,
                                              const float* __restrict__ asrc,
                                              const float* __restrict__ adst,
                                              __hip_bfloat16* __restrict__ hWb,
                                              float* __restrict__ esrc,
                                              float* __restrict__ edst) {
    __shared__ __align__(16) float hrow[16][HID + 4];
    int n0 = blockIdx.x * 16, t = threadIdx.x;
    for (int i = t; i < 16 * HID; i += 128) hrow[i >> 7][i & 127] = hin[n0 * HID + i];
    __syncthreads();

    {
        int node = t >> 3, lane = t & 7;
        float s1 = 0.f, s2 = 0.f;
        #pragma unroll
        for (int j = 0; j < 16; ++j) {
            float v = hrow[node][lane + 8 * j];
            s1 += v; s2 += v * v;
        }
        #pragma unroll
        for (int m = 1; m < 8; m <<= 1) {
            s1 += __shfl_xor(s1, m, 8);
            s2 += __shfl_xor(s2, m, 8);
        }
        float mu  = s1 * (1.0f / 128.0f);
        float var = s2 * (1.0f / 128.0f) - mu * mu;
        float rs  = rsqrtf(var + 1e-5f);
        #pragma unroll
        for (int j = 0; j < 16; ++j) {
            int col = lane + 8 * j;
            float v = hrow[node][col];
            float y = (v - mu) * rs * g[col] + be[col];
            hrow[node][col] = gelu_tanh(y);
        }
    }
    __syncthreads();

    float acc[16];
    #pragma unroll
    for (int r = 0; r < 16; ++r) acc[r] = 0.f;
    const float4* h4 = reinterpret_cast<const float4*>(&hrow[0][0]);
    for (int k4 = 0; k4 < HID / 4; ++k4) {
        int k = k4 * 4;
        float w0 = W[(k + 0) * HID + t];
        float w1 = W[(k + 1) * HID + t];
        float w2 = W[(k + 2) * HID + t];
        float w3 = W[(k + 3) * HID + t];
        #pragma unroll
        for (int r = 0; r < 16; ++r) {
            float4 hv = h4[r * ((HID + 4) / 4) + k4];
            acc[r] = fmaf(hv.x, w0, fmaf(hv.y, w1, fmaf(hv.z, w2, fmaf(hv.w, w3, acc[r]))));
        }
    }
    float as = asrc[t], ad = adst[t];
    #pragma unroll
    for (int r = 0; r < 16; ++r) {
        hWb[(n0 + r) * HID + t] = __float2bfloat16(acc[r]);
        float v1 = acc[r] * as, v2 = acc[r] * ad;
        #pragma unroll
        for (int m = 1; m < 32; m <<= 1) {
            v1 += __shfl_xor(v1, m, 32);
            v2 += __shfl_xor(v2, m, 32);
        }
        if ((t & 31) == 0) {
            esrc[(n0 + r) * 4 + (t >> 5)] = v1;
            edst[(n0 + r) * 4 + (t >> 5)] = v2;
        }
    }
}

// ------- edge-parallel attention weights: wexp[e][h] = exp(lrelu(esrc+edst)) (bf16) -------

__global__ __launch_bounds__(256) void k_edgew(const int* __restrict__ csr,
                                               const int* __restrict__ dstid,
                                               const float* __restrict__ esrc,
                                               const float* __restrict__ edst,
                                               ushort* __restrict__ wexp) {
    int i = blockIdx.x * 256 + threadIdx.x;
    if (i >= ETOT) return;
    int s = csr[i], d = dstid[i];
    float4 es = reinterpret_cast<const float4*>(esrc)[s];
    float4 ed = reinterpret_cast<const float4*>(edst)[d];
    float e0 = es.x + ed.x, e1 = es.y + ed.y, e2 = es.z + ed.z, e3 = es.w + ed.w;
    e0 = __expf(fmaxf(e0, 0.2f * e0));
    e1 = __expf(fmaxf(e1, 0.2f * e1));
    e2 = __expf(fmaxf(e2, 0.2f * e2));
    e3 = __expf(fmaxf(e3, 0.2f * e3));
    __hip_bfloat16 b0 = __float2bfloat16(e0), b1 = __float2bfloat16(e1);
    __hip_bfloat16 b2 = __float2bfloat16(e2), b3 = __float2bfloat16(e3);
    ushort4 pk;
    pk.x = *(ushort*)&b0; pk.y = *(ushort*)&b1; pk.z = *(ushort*)&b2; pk.w = *(ushort*)&b3;
    reinterpret_cast<ushort4*>(wexp)[i] = pk;
}

// ------- GAT aggregate: barrier-free, 3-stage software-pipelined gather loop -------
// 128 thr = 2 waves x 4 edge-slots x 16 lane-groups; lane group q holds cols 8q..8q+7.
// Pipeline: src/w for it+2, row for it+1 in flight while FMAing it.

__global__ __launch_bounds__(128) void k_gat(const __hip_bfloat16* __restrict__ hWb,
                                             const ushort* __restrict__ wexp,
                                             const int* __restrict__ off,
                                             const int* __restrict__ csr,
                                             const float* __restrict__ bg,
                                             float* __restrict__ out) {
    __shared__ float redA[16][8];
    __shared__ float redD[16];
    int n = blockIdx.x, t = threadIdx.x;
    int wv = t >> 6, l = t & 63;
    int slot = l >> 4;          // lane bits 4-5 = edge slot
    int q    = l & 15;          // col group: cols 8q..8q+7
    int hq   = q >> 2;          // head of those cols
    int o0 = off[n], o1 = off[n + 1];
    int deg = o1 - o0;
    const uint4* hw4 = reinterpret_cast<const uint4*>(hWb);
    float acc[8] = {0.f, 0.f, 0.f, 0.f, 0.f, 0.f, 0.f, 0.f};
    float dsum = 0.f;
    int nIter = (deg + 7) >> 3;
    int e = o0 + wv * 4 + slot;

    // prologue: stage A (row in flight), stage B (src/w in flight)
    int e0 = min(e, ETOT - 1);
    int e1 = min(e + 8, ETOT - 1);
    int    srcA = csr[e0];
    ushort ubA  = wexp[e0 * 4 + hq];
    int    srcB = csr[e1];
    ushort ubB  = wexp[e1 * 4 + hq];
    uint4  rA   = hw4[srcA * 16 + q];

    for (int it = 0; it < nIter; ++it) {
        uint4 rB = hw4[srcB * 16 + q];          // row for it+1
        int ec2 = min(e + 16, ETOT - 1);        // src/w for it+2
        int    srcC = csr[ec2];
        ushort ubC  = wexp[ec2 * 4 + hq];
        float w = (e < o1) ? __uint_as_float(((unsigned)ubA) << 16) : 0.f;
        acc[0] = fmaf(w, __uint_as_float(rA.x << 16),          acc[0]);
        acc[1] = fmaf(w, __uint_as_float(rA.x & 0xffff0000u),  acc[1]);
        acc[2] = fmaf(w, __uint_as_float(rA.y << 16),          acc[2]);
        acc[3] = fmaf(w, __uint_as_float(rA.y & 0xffff0000u),  acc[3]);
        acc[4] = fmaf(w, __uint_as_float(rA.z << 16),          acc[4]);
        acc[5] = fmaf(w, __uint_as_float(rA.z & 0xffff0000u),  acc[5]);
        acc[6] = fmaf(w, __uint_as_float(rA.w << 16),          acc[6]);
        acc[7] = fmaf(w, __uint_as_float(rA.w & 0xffff0000u),  acc[7]);
        dsum += w;
        e += 8;
        srcA = srcB; ubA = ubB; rA = rB;
        srcB = srcC; ubB = ubC;
    }
    // reduce across the 4 edge slots (lane bits 4 and 5)
    #pragma unroll
    for (int m = 16; m <= 32; m <<= 1) {
        #pragma unroll
        for (int j = 0; j < 8; ++j) acc[j] += __shfl_xor(acc[j], m, 64);
        dsum += __shfl_xor(dsum, m, 64);
    }
    if (wv == 1 && l < 16) {
        #pragma unroll
        for (int j = 0; j < 8; ++j) redA[l][j] = acc[j];
        redD[l] = dsum;
    }
    __syncthreads();
    if (wv == 0 && l < 16) {
        float inv = 1.0f / (dsum + redD[l]);
        float4 r0, r1;
        r0.x = (acc[0] + redA[l][0]) * inv + bg[l * 8 + 0];
        r0.y = (acc[1] + redA[l][1]) * inv + bg[l * 8 + 1];
        r0.z = (acc[2] + redA[l][2]) * inv + bg[l * 8 + 2];
        r0.w = (acc[3] + redA[l][3]) * inv + bg[l * 8 + 3];
        r1.x = (acc[4] + redA[l][4]) * inv + bg[l * 8 + 4];
        r1.y = (acc[5] + redA[l][5]) * inv + bg[l * 8 + 5];
        r1.z = (acc[6] + redA[l][6]) * inv + bg[l * 8 + 6];
        r1.w = (acc[7] + redA[l][7]) * inv + bg[l * 8 + 7];
        float4* op = reinterpret_cast<float4*>(out + n * HID + l * 8);
        op[0] = r0; op[1] = r1;
    }
}

// ---------------- output linear (16 nodes/block) ----------------

__global__ __launch_bounds__(64) void k_out(const float* __restrict__ h,
                                            const float* __restrict__ w,
                                            const float* __restrict__ b,
                                            float* __restrict__ out) {
    __shared__ __align__(16) float hr[16][HID];
    int n0 = blockIdx.x * 16, t = threadIdx.x;
    for (int i = t; i < 16 * HID; i += 64) hr[i >> 7][i & 127] = h[n0 * HID + i];
    __syncthreads();
    float acc[16];
    float bb = b[t];
    #pragma unroll
    for (int r = 0; r < 16; ++r) acc[r] = bb;
    const float4* h4 = reinterpret_cast<const float4*>(&hr[0][0]);
    for (int k4 = 0; k4 < HID / 4; ++k4) {
        int k = k4 * 4;
        float w0 = w[(k + 0) * OUTF + t];
        float w1 = w[(k + 1) * OUTF + t];
        float w2 = w[(k + 2) * OUTF + t];
        float w3 = w[(k + 3) * OUTF + t];
        #pragma unroll
        for (int r = 0; r < 16; ++r) {
            float4 hv = h4[r * (HID / 4) + k4];
            acc[r] = fmaf(hv.x, w0, fmaf(hv.y, w1, fmaf(hv.z, w2, fmaf(hv.w, w3, acc[r]))));
        }
    }
    #pragma unroll
    for (int r = 0; r < 16; ++r) out[(n0 + r) * OUTF + t] = acc[r];
}

extern "C" void kernel_launch(void* const* d_in, const int* in_sizes, int n_in,
                              void* d_out, int out_size, void* d_ws, size_t ws_size,
                              hipStream_t stream) {
    const float* x    = (const float*)d_in[0];
    const int*   ei   = (const int*)  d_in[1];   // [2, E] int32
    const float* w_in = (const float*)d_in[2];
    const float* b_in = (const float*)d_in[3];
    const float* g1   = (const float*)d_in[4];
    const float* be1  = (const float*)d_in[5];
    const float* W1   = (const float*)d_in[6];
    const float* as1  = (const float*)d_in[7];
    const float* ad1  = (const float*)d_in[8];
    const float* bg1  = (const float*)d_in[9];
    const float* g2   = (const float*)d_in[10];
    const float* be2  = (const float*)d_in[11];
    const float* W2   = (const float*)d_in[12];
    const float* as2  = (const float*)d_in[13];
    const float* ad2  = (const float*)d_in[14];
    const float* bg2  = (const float*)d_in[15];
    const float* w_o  = (const float*)d_in[16];
    const float* b_o  = (const float*)d_in[17];
    float* out = (float*)d_out;

    char* p = (char*)d_ws;
    auto take = [&](size_t bytes) {
        void* r = p;
        p += (bytes + 255) & ~(size_t)255;
        return r;
    };
    float*          gout  = (float*)take((size_t)NN * HID * 4);
    float*          h2    = (float*)take((size_t)NN * HID * 4);
    __hip_bfloat16* hWb   = (__hip_bfloat16*)take((size_t)NN * HID * 2);
    float*          esrc  = (float*)take((size_t)NN * 4 * 4);
    float*          edst  = (float*)take((size_t)NN * 4 * 4);
    int*            off   = (int*)take((size_t)(NN + 1) * 4);
    int*            csr   = (int*)take((size_t)ETOT * 4);
    int*            dstid = (int*)take((size_t)ETOT * 4);
    // wexp (ETOT ushort4 = 13.2 MB) aliases tmp (12.6 MB): build finishes before use
    size_t ovl = (size_t)ETOT * 8;
    size_t tsz = (size_t)NBK * CAP * 4;
    ushort*         wexp  = (ushort*)take(ovl > tsz ? ovl : tsz);
    int*            tmp   = (int*)wexp;
    int*            bcur  = (int*)take((size_t)NBK * 4);
    int*            bstart= (int*)take((size_t)NBK * 4);

    k_zero      <<<(NBK + 255) / 256, 256, 0, stream>>>(bcur);
    k_bucket    <<<BBLK, 1024, 0, stream>>>(ei, bcur, tmp);
    k_bscan     <<<1, NBK, 0, stream>>>(bcur, bstart, off);
    k_bucket2csr<<<NBK, 256, 0, stream>>>(tmp, bcur, bstart, off, csr, dstid);

    k_infeat<<<NN / 16, 128, 0, stream>>>(x, w_in, b_in, g1, be1, W1, as1, ad1, hWb, esrc, edst);
    k_edgew <<<(ETOT + 255) / 256, 256, 0, stream>>>(csr, dstid, esrc, edst, wexp);
    k_gat   <<<NN, 128, 0, stream>>>(hWb, wexp, off, csr, bg1, gout);
    k_feat  <<<NN / 16, 128, 0, stream>>>(gout, g2, be2, W2, as2, ad2, hWb, esrc, edst);
    k_edgew <<<(ETOT + 255) / 256, 256, 0, stream>>>(csr, dstid, esrc, edst, wexp);
    k_gat   <<<NN, 128, 0, stream>>>(hWb, wexp, off, csr, bg2, h2);
    k_out   <<<NN / 16, 64, 0, stream>>>(h2, w_o, b_o, out);
}

// Round 6
// 363.507 us; speedup vs baseline: 1.2180x; 1.2180x over previous
//
#include <hip/hip_runtime.h>
#include <hip/hip_bf16.h>
#include <math.h>

#define NN   50000
#define EE   1600000
#define ETOT (EE + NN)
#define HID  128
#define INF_ 64
#define OUTF 64

// bucketed CSR build
#define NBK  1024   // buckets (contiguous dst ranges)
#define NPB  49     // nodes per bucket (1024*49 = 50176 >= NN)
#define CAP  3072   // per-bucket capacity; mean ~1617, 1.9x headroom
#define BBLK 128    // blocks for k_bucket
#define CHUNK ((ETOT + BBLK - 1) / BBLK)   // 12891 edges per block

#define PADX 72     // xbf row stride (ushorts), 144 B (16B-aligned)
#define PADH 136    // hbf row stride (ushorts), 272 B (16B-aligned)

typedef short  short8  __attribute__((ext_vector_type(8)));
typedef float  floatx4 __attribute__((ext_vector_type(4)));

__device__ __forceinline__ ushort f2b(float f) {
    __hip_bfloat16 h = __float2bfloat16(f);
    return *reinterpret_cast<ushort*>(&h);
}

// fast tanh-gelu: gelu(x) = x * t/(t+1), t = exp(2u), u = 0.79788456*(x+0.044715x^3)
__device__ __forceinline__ float gelu_f(float x) {
    float x2 = x * x;
    float u  = 0.7978845608f * fmaf(0.044715f * x2, x, x);
    u = fminf(u, 40.f);                 // overflow guard (LN'd inputs never get here)
    float t = __expf(2.f * u);
    return x * t / (t + 1.f);
}

// ---------------- CSR build (bucketed counting sort) ----------------

__global__ void k_zero(int* bcur) {
    int i = blockIdx.x * 256 + threadIdx.x;
    if (i < NBK) bcur[i] = 0;
}

__global__ __launch_bounds__(1024) void k_bucket(const int* __restrict__ ei,
                                                 int* bcur, int* __restrict__ tmp) {
    __shared__ unsigned sortedv[CHUNK];
    __shared__ int hist[NBK], gbase[NBK], loff[NBK], lcur[NBK];
    int t = threadIdx.x;
    int lo = blockIdx.x * CHUNK;
    int hi = min(lo + CHUNK, ETOT);
    int bsize = hi - lo;
    hist[t] = 0;
    __syncthreads();
    for (int i = lo + t; i < hi; i += 1024) {
        int d = (i < EE) ? ei[EE + i] : i - EE;
        atomicAdd(&hist[d / NPB], 1);
    }
    __syncthreads();
    {
        int c = hist[t];
        gbase[t] = (c > 0) ? atomicAdd(&bcur[t], c) : 0;
        loff[t] = c;
    }
    __syncthreads();
    for (int d = 1; d < NBK; d <<= 1) {
        int v = (t >= d) ? loff[t - d] : 0;
        __syncthreads();
        loff[t] += v;
        __syncthreads();
    }
    {
        int ex = loff[t] - hist[t];
        __syncthreads();
        loff[t] = ex;
        lcur[t] = ex;
    }
    __syncthreads();
    for (int i = lo + t; i < hi; i += 1024) {
        unsigned s, d;
        if (i < EE) { s = (unsigned)ei[i]; d = (unsigned)ei[EE + i]; }
        else        { s = d = (unsigned)(i - EE); }
        unsigned b = d / NPB;
        int p = atomicAdd(&lcur[b], 1);
        sortedv[p] = (b << 22) | (s << 6) | (d - b * NPB);
    }
    __syncthreads();
    for (int i = t; i < bsize; i += 1024) {
        unsigned v = sortedv[i];
        unsigned b = v >> 22;
        int pp = gbase[b] + i - loff[b];
        if (pp < CAP) tmp[b * CAP + pp] = (int)(v & 0x3FFFFFu);
    }
}

__global__ __launch_bounds__(1024) void k_bscan(const int* __restrict__ bcur,
                                                int* __restrict__ bstart,
                                                int* __restrict__ off) {
    __shared__ int s[NBK];
    int t = threadIdx.x;
    int v0 = bcur[t];
    s[t] = v0;
    __syncthreads();
    for (int d = 1; d < NBK; d <<= 1) {
        int v = (t >= d) ? s[t - d] : 0;
        __syncthreads();
        s[t] += v;
        __syncthreads();
    }
    bstart[t] = s[t] - v0;
    if (t == 0) off[NN] = ETOT;
}

__global__ __launch_bounds__(256) void k_bucket2csr(const int* __restrict__ tmp,
                                                    const int* __restrict__ bcur,
                                                    const int* __restrict__ bstart,
                                                    int* __restrict__ off,
                                                    int* __restrict__ csr,
                                                    int* __restrict__ dstid) {
    __shared__ int sE[CAP];
    __shared__ int lcnt[NPB];
    __shared__ int loff[NPB];
    int b = blockIdx.x, t = threadIdx.x;
    int n0    = b * NPB;
    int bsize = min(bcur[b], CAP);
    int base  = bstart[b];
    if (t < NPB) lcnt[t] = 0;
    for (int i = t; i < bsize; i += 256) sE[i] = tmp[b * CAP + i];
    __syncthreads();
    for (int i = t; i < bsize; i += 256) atomicAdd(&lcnt[sE[i] & 63], 1);
    __syncthreads();
    if (t == 0) {
        int run = 0;
        for (int j = 0; j < NPB; ++j) { loff[j] = run; run += lcnt[j]; }
    }
    __syncthreads();
    if (t < NPB) {
        if (n0 + t < NN) off[n0 + t] = base + loff[t];
        lcnt[t] = loff[t];
    }
    __syncthreads();
    for (int i = t; i < bsize; i += 256) {
        int v   = sE[i];
        int d   = v & 63;
        int pos = base + atomicAdd(&lcnt[d], 1);
        csr[pos]   = v >> 6;
        dstid[pos] = n0 + d;
    }
}

// ---------------- weight packing into MFMA B-fragment order ----------------
// frag index (T*kst + s)*64 + l holds B[k = s*32 + (l>>4)*8 + j][n = T*16 + (l&15)], j=0..7

__global__ void k_pack(const float* __restrict__ W, ushort* __restrict__ dst,
                       int K, int N) {
    int tid = blockIdx.x * 256 + threadIdx.x;
    int kst = K >> 5;
    int total = (N >> 4) * kst * 64;
    if (tid >= total) return;
    int l = tid & 63;
    int s = (tid >> 6) % kst;
    int T = tid / (kst * 64);
    int m = l & 15, q = l >> 4;
    ushort o[8];
    #pragma unroll
    for (int j = 0; j < 8; ++j)
        o[j] = f2b(W[(s * 32 + q * 8 + j) * N + T * 16 + m]);
    uint4 pk;
    pk.x = (unsigned)o[0] | ((unsigned)o[1] << 16);
    pk.y = (unsigned)o[2] | ((unsigned)o[3] << 16);
    pk.z = (unsigned)o[4] | ((unsigned)o[5] << 16);
    pk.w = (unsigned)o[6] | ((unsigned)o[7] << 16);
    reinterpret_cast<uint4*>(dst)[tid] = pk;
}

// ------- MFMA fused: x@w_in -> +bias -> LN -> GELU -> @W -> hWb + scores -------
// 128 thr = 2 waves; each wave owns 16 nodes, full 128 cols via 8 tiles x 4 ksteps.

__global__ __launch_bounds__(128) void k_infeat(const float* __restrict__ x,
                                                const ushort* __restrict__ Bp1,
                                                const float* __restrict__ bin,
                                                const float* __restrict__ g,
                                                const float* __restrict__ be,
                                                const ushort* __restrict__ Bp2,
                                                const float* __restrict__ asrc,
                                                const float* __restrict__ adst,
                                                ushort* __restrict__ hWb,
                                                float* __restrict__ esrc,
                                                float* __restrict__ edst) {
    __shared__ ushort xbf[2][16 * PADX];
    __shared__ ushort hbf[2][16 * PADH];
    int t = threadIdx.x, w = t >> 6, l = t & 63;
    int m = l & 15, q = l >> 4;
    int n0w = blockIdx.x * 32 + w * 16;
    bool active = (n0w < NN);
    int nb = active ? n0w : 0;

    // stage x (16 nodes x 64 cols) as bf16
    const float4* x4 = reinterpret_cast<const float4*>(x) + (size_t)nb * 16;
    #pragma unroll
    for (int i = 0; i < 4; ++i) {
        int f4 = l + 64 * i;
        int node = f4 >> 4, c4 = f4 & 15;
        float4 v = x4[f4];
        ushort4 pk = { f2b(v.x), f2b(v.y), f2b(v.z), f2b(v.w) };
        *reinterpret_cast<ushort4*>(&xbf[w][node * PADX + c4 * 4]) = pk;
    }
    __syncthreads();

    // GEMM1: 8 tiles x 2 ksteps
    const short8* B1 = reinterpret_cast<const short8*>(Bp1);
    floatx4 acc1[8];
    #pragma unroll
    for (int T = 0; T < 8; ++T) acc1[T] = (floatx4){0.f, 0.f, 0.f, 0.f};
    #pragma unroll
    for (int s = 0; s < 2; ++s) {
        short8 a = *reinterpret_cast<const short8*>(&xbf[w][m * PADX + s * 32 + q * 8]);
        #pragma unroll
        for (int T = 0; T < 8; ++T) {
            short8 b = B1[(T * 2 + s) * 64 + l];
            acc1[T] = __builtin_amdgcn_mfma_f32_16x16x32_bf16(a, b, acc1[T], 0, 0, 0);
        }
    }

    // bias + LN (rows q*4+j live across the 16 lanes of this quad) + GELU -> hbf
    float bc[8], gc[8], bec[8];
    #pragma unroll
    for (int T = 0; T < 8; ++T) {
        int c = T * 16 + m;
        bc[T] = bin[c]; gc[T] = g[c]; bec[T] = be[c];
    }
    #pragma unroll
    for (int j = 0; j < 4; ++j) {
        float s1 = 0.f, s2 = 0.f;
        #pragma unroll
        for (int T = 0; T < 8; ++T) {
            float v = acc1[T][j] + bc[T];
            s1 += v; s2 = fmaf(v, v, s2);
        }
        #pragma unroll
        for (int mk = 1; mk < 16; mk <<= 1) {
            s1 += __shfl_xor(s1, mk, 64);
            s2 += __shfl_xor(s2, mk, 64);
        }
        float mu = s1 * (1.f / 128.f);
        float var = s2 * (1.f / 128.f) - mu * mu;
        float rs = rsqrtf(var + 1e-5f);
        #pragma unroll
        for (int T = 0; T < 8; ++T) {
            float v = acc1[T][j] + bc[T];
            float y = (v - mu) * rs * gc[T] + bec[T];
            hbf[w][(q * 4 + j) * PADH + T * 16 + m] = f2b(gelu_f(y));
        }
    }
    __syncthreads();

    // GEMM2: 8 tiles x 4 ksteps
    const short8* B2 = reinterpret_cast<const short8*>(Bp2);
    floatx4 acc2[8];
    #pragma unroll
    for (int T = 0; T < 8; ++T) acc2[T] = (floatx4){0.f, 0.f, 0.f, 0.f};
    #pragma unroll
    for (int s = 0; s < 4; ++s) {
        short8 a = *reinterpret_cast<const short8*>(&hbf[w][m * PADH + s * 32 + q * 8]);
        #pragma unroll
        for (int T = 0; T < 8; ++T) {
            short8 b = B2[(T * 4 + s) * 64 + l];
            acc2[T] = __builtin_amdgcn_mfma_f32_16x16x32_bf16(a, b, acc2[T], 0, 0, 0);
        }
    }

    // epilogue: hWb stores + per-head scores
    float as_[8], ad_[8];
    #pragma unroll
    for (int T = 0; T < 8; ++T) {
        int c = T * 16 + m;
        as_[T] = asrc[c]; ad_[T] = adst[c];
    }
    if (active) {
        #pragma unroll
        for (int j = 0; j < 4; ++j)
            #pragma unroll
            for (int T = 0; T < 8; ++T)
                hWb[(size_t)(n0w + q * 4 + j) * HID + T * 16 + m] = f2b(acc2[T][j]);
    }
    #pragma unroll
    for (int j = 0; j < 4; ++j) {
        #pragma unroll
        for (int h = 0; h < 4; ++h) {
            float v1 = fmaf(acc2[2 * h][j], as_[2 * h], acc2[2 * h + 1][j] * as_[2 * h + 1]);
            float v2 = fmaf(acc2[2 * h][j], ad_[2 * h], acc2[2 * h + 1][j] * ad_[2 * h + 1]);
            #pragma unroll
            for (int mk = 1; mk < 16; mk <<= 1) {
                v1 += __shfl_xor(v1, mk, 64);
                v2 += __shfl_xor(v2, mk, 64);
            }
            if (m == 0 && active) {
                esrc[(n0w + q * 4 + j) * 4 + h] = v1;
                edst[(n0w + q * 4 + j) * 4 + h] = v2;
            }
        }
    }
}

// ------- MFMA fused layer-2: LN(gout) -> GELU -> @W2 -> hWb + scores -------

__global__ __launch_bounds__(128) void k_feat(const float* __restrict__ hin,
                                              const float* __restrict__ g,
                                              const float* __restrict__ be,
                                              const ushort* __restrict__ Bp2,
                                              const float* __restrict__ asrc,
                                              const float* __restrict__ adst,
                                              ushort* __restrict__ hWb,
                                              float* __restrict__ esrc,
                                              float* __restrict__ edst) {
    __shared__ ushort hbf[2][16 * PADH];
    int t = threadIdx.x, w = t >> 6, l = t & 63;
    int m = l & 15, q = l >> 4;
    int n0w = blockIdx.x * 32 + w * 16;
    bool active = (n0w < NN);
    int nb = active ? n0w : 0;

    // load 16x128 fp32, LN per row (row spans one half-wave per iter), GELU, store bf16
    const float4* h4g = reinterpret_cast<const float4*>(hin) + (size_t)nb * 32;
    const float4* g4  = reinterpret_cast<const float4*>(g);
    const float4* be4 = reinterpret_cast<const float4*>(be);
    #pragma unroll
    for (int i = 0; i < 8; ++i) {
        int f4 = l + 64 * i;
        int node = f4 >> 5, c4 = f4 & 31;
        float4 v = h4g[f4];
        float s1 = v.x + v.y + v.z + v.w;
        float s2 = fmaf(v.x, v.x, fmaf(v.y, v.y, fmaf(v.z, v.z, v.w * v.w)));
        #pragma unroll
        for (int mk = 1; mk < 32; mk <<= 1) {
            s1 += __shfl_xor(s1, mk, 64);
            s2 += __shfl_xor(s2, mk, 64);
        }
        float mu = s1 * (1.f / 128.f);
        float var = s2 * (1.f / 128.f) - mu * mu;
        float rs = rsqrtf(var + 1e-5f);
        float4 gg = g4[c4], bb = be4[c4];
        ushort4 pk;
        pk.x = f2b(gelu_f((v.x - mu) * rs * gg.x + bb.x));
        pk.y = f2b(gelu_f((v.y - mu) * rs * gg.y + bb.y));
        pk.z = f2b(gelu_f((v.z - mu) * rs * gg.z + bb.z));
        pk.w = f2b(gelu_f((v.w - mu) * rs * gg.w + bb.w));
        *reinterpret_cast<ushort4*>(&hbf[w][node * PADH + c4 * 4]) = pk;
    }
    __syncthreads();

    const short8* B2 = reinterpret_cast<const short8*>(Bp2);
    floatx4 acc2[8];
    #pragma unroll
    for (int T = 0; T < 8; ++T) acc2[T] = (floatx4){0.f, 0.f, 0.f, 0.f};
    #pragma unroll
    for (int s = 0; s < 4; ++s) {
        short8 a = *reinterpret_cast<const short8*>(&hbf[w][m * PADH + s * 32 + q * 8]);
        #pragma unroll
        for (int T = 0; T < 8; ++T) {
            short8 b = B2[(T * 4 + s) * 64 + l];
            acc2[T] = __builtin_amdgcn_mfma_f32_16x16x32_bf16(a, b, acc2[T], 0, 0, 0);
        }
    }

    float as_[8], ad_[8];
    #pragma unroll
    for (int T = 0; T < 8; ++T) {
        int c = T * 16 + m;
        as_[T] = asrc[c]; ad_[T] = adst[c];
    }
    if (active) {
        #pragma unroll
        for (int j = 0; j < 4; ++j)
            #pragma unroll
            for (int T = 0; T < 8; ++T)
                hWb[(size_t)(n0w + q * 4 + j) * HID + T * 16 + m] = f2b(acc2[T][j]);
    }
    #pragma unroll
    for (int j = 0; j < 4; ++j) {
        #pragma unroll
        for (int h = 0; h < 4; ++h) {
            float v1 = fmaf(acc2[2 * h][j], as_[2 * h], acc2[2 * h + 1][j] * as_[2 * h + 1]);
            float v2 = fmaf(acc2[2 * h][j], ad_[2 * h], acc2[2 * h + 1][j] * ad_[2 * h + 1]);
            #pragma unroll
            for (int mk = 1; mk < 16; mk <<= 1) {
                v1 += __shfl_xor(v1, mk, 64);
                v2 += __shfl_xor(v2, mk, 64);
            }
            if (m == 0 && active) {
                esrc[(n0w + q * 4 + j) * 4 + h] = v1;
                edst[(n0w + q * 4 + j) * 4 + h] = v2;
            }
        }
    }
}

// ------- edge-parallel attention weights -------

__global__ __launch_bounds__(256) void k_edgew(const int* __restrict__ csr,
                                               const int* __restrict__ dstid,
                                               const float* __restrict__ esrc,
                                               const float* __restrict__ edst,
                                               ushort* __restrict__ wexp) {
    int i = blockIdx.x * 256 + threadIdx.x;
    if (i >= ETOT) return;
    int s = csr[i], d = dstid[i];
    float4 es = reinterpret_cast<const float4*>(esrc)[s];
    float4 ed = reinterpret_cast<const float4*>(edst)[d];
    float e0 = es.x + ed.x, e1 = es.y + ed.y, e2 = es.z + ed.z, e3 = es.w + ed.w;
    e0 = __expf(fmaxf(e0, 0.2f * e0));
    e1 = __expf(fmaxf(e1, 0.2f * e1));
    e2 = __expf(fmaxf(e2, 0.2f * e2));
    e3 = __expf(fmaxf(e3, 0.2f * e3));
    ushort4 pk = { f2b(e0), f2b(e1), f2b(e2), f2b(e3) };
    reinterpret_cast<ushort4*>(wexp)[i] = pk;
}

// ------- GAT aggregate: barrier-free, 3-stage software-pipelined gather loop -------

__global__ __launch_bounds__(128) void k_gat(const ushort* __restrict__ hWb,
                                             const ushort* __restrict__ wexp,
                                             const int* __restrict__ off,
                                             const int* __restrict__ csr,
                                             const float* __restrict__ bg,
                                             float* __restrict__ out) {
    __shared__ float redA[16][8];
    __shared__ float redD[16];
    int n = blockIdx.x, t = threadIdx.x;
    int wv = t >> 6, l = t & 63;
    int slot = l >> 4;
    int q    = l & 15;
    int hq   = q >> 2;
    int o0 = off[n], o1 = off[n + 1];
    int deg = o1 - o0;
    const uint4* hw4 = reinterpret_cast<const uint4*>(hWb);
    float acc[8] = {0.f, 0.f, 0.f, 0.f, 0.f, 0.f, 0.f, 0.f};
    float dsum = 0.f;
    int nIter = (deg + 7) >> 3;
    int e = o0 + wv * 4 + slot;

    int e0 = min(e, ETOT - 1);
    int e1 = min(e + 8, ETOT - 1);
    int    srcA = csr[e0];
    ushort ubA  = wexp[e0 * 4 + hq];
    int    srcB = csr[e1];
    ushort ubB  = wexp[e1 * 4 + hq];
    uint4  rA   = hw4[srcA * 16 + q];

    for (int it = 0; it < nIter; ++it) {
        uint4 rB = hw4[srcB * 16 + q];
        int ec2 = min(e + 16, ETOT - 1);
        int    srcC = csr[ec2];
        ushort ubC  = wexp[ec2 * 4 + hq];
        float w = (e < o1) ? __uint_as_float(((unsigned)ubA) << 16) : 0.f;
        acc[0] = fmaf(w, __uint_as_float(rA.x << 16),          acc[0]);
        acc[1] = fmaf(w, __uint_as_float(rA.x & 0xffff0000u),  acc[1]);
        acc[2] = fmaf(w, __uint_as_float(rA.y << 16),          acc[2]);
        acc[3] = fmaf(w, __uint_as_float(rA.y & 0xffff0000u),  acc[3]);
        acc[4] = fmaf(w, __uint_as_float(rA.z << 16),          acc[4]);
        acc[5] = fmaf(w, __uint_as_float(rA.z & 0xffff0000u),  acc[5]);
        acc[6] = fmaf(w, __uint_as_float(rA.w << 16),          acc[6]);
        acc[7] = fmaf(w, __uint_as_float(rA.w & 0xffff0000u),  acc[7]);
        dsum += w;
        e += 8;
        srcA = srcB; ubA = ubB; rA = rB;
        srcB = srcC; ubB = ubC;
    }
    #pragma unroll
    for (int mk = 16; mk <= 32; mk <<= 1) {
        #pragma unroll
        for (int j = 0; j < 8; ++j) acc[j] += __shfl_xor(acc[j], mk, 64);
        dsum += __shfl_xor(dsum, mk, 64);
    }
    if (wv == 1 && l < 16) {
        #pragma unroll
        for (int j = 0; j < 8; ++j) redA[l][j] = acc[j];
        redD[l] = dsum;
    }
    __syncthreads();
    if (wv == 0 && l < 16) {
        float inv = 1.0f / (dsum + redD[l]);
        float4 r0, r1;
        r0.x = (acc[0] + redA[l][0]) * inv + bg[l * 8 + 0];
        r0.y = (acc[1] + redA[l][1]) * inv + bg[l * 8 + 1];
        r0.z = (acc[2] + redA[l][2]) * inv + bg[l * 8 + 2];
        r0.w = (acc[3] + redA[l][3]) * inv + bg[l * 8 + 3];
        r1.x = (acc[4] + redA[l][4]) * inv + bg[l * 8 + 4];
        r1.y = (acc[5] + redA[l][5]) * inv + bg[l * 8 + 5];
        r1.z = (acc[6] + redA[l][6]) * inv + bg[l * 8 + 6];
        r1.w = (acc[7] + redA[l][7]) * inv + bg[l * 8 + 7];
        float4* op = reinterpret_cast<float4*>(out + (size_t)n * HID + l * 8);
        op[0] = r0; op[1] = r1;
    }
}

// ---------------- output linear: fp32 register-tiled 4 nodes x 4 cols ----------------

__global__ __launch_bounds__(64) void k_out(const float* __restrict__ h,
                                            const float* __restrict__ w,
                                            const float* __restrict__ b,
                                            float* __restrict__ out) {
    __shared__ __align__(16) float hr[16 * 132];
    int t = threadIdx.x, n0 = blockIdx.x * 16;
    const float4* h4g = reinterpret_cast<const float4*>(h) + (size_t)n0 * 32;
    float4* hr4 = reinterpret_cast<float4*>(hr);
    #pragma unroll
    for (int i = 0; i < 8; ++i) {
        int f4 = t + 64 * i;
        hr4[(f4 >> 5) * 33 + (f4 & 31)] = h4g[f4];
    }
    __syncthreads();
    int cg = t & 15, ng = t >> 4;
    const float4* w4 = reinterpret_cast<const float4*>(w);
    float4 bb = reinterpret_cast<const float4*>(b)[cg];
    float4 acc[4] = {bb, bb, bb, bb};
    for (int k4 = 0; k4 < 32; ++k4) {
        float4 w0 = w4[(k4 * 4 + 0) * 16 + cg];
        float4 w1 = w4[(k4 * 4 + 1) * 16 + cg];
        float4 w2 = w4[(k4 * 4 + 2) * 16 + cg];
        float4 w3 = w4[(k4 * 4 + 3) * 16 + cg];
        #pragma unroll
        for (int r = 0; r < 4; ++r) {
            float4 hv = hr4[(ng * 4 + r) * 33 + k4];
            acc[r].x = fmaf(hv.x, w0.x, fmaf(hv.y, w1.x, fmaf(hv.z, w2.x, fmaf(hv.w, w3.x, acc[r].x))));
            acc[r].y = fmaf(hv.x, w0.y, fmaf(hv.y, w1.y, fmaf(hv.z, w2.y, fmaf(hv.w, w3.y, acc[r].y))));
            acc[r].z = fmaf(hv.x, w0.z, fmaf(hv.y, w1.z, fmaf(hv.z, w2.z, fmaf(hv.w, w3.z, acc[r].z))));
            acc[r].w = fmaf(hv.x, w0.w, fmaf(hv.y, w1.w, fmaf(hv.z, w2.w, fmaf(hv.w, w3.w, acc[r].w))));
        }
    }
    float4* o4 = reinterpret_cast<float4*>(out) + (size_t)n0 * 16;
    #pragma unroll
    for (int r = 0; r < 4; ++r) o4[(ng * 4 + r) * 16 + cg] = acc[r];
}

extern "C" void kernel_launch(void* const* d_in, const int* in_sizes, int n_in,
                              void* d_out, int out_size, void* d_ws, size_t ws_size,
                              hipStream_t stream) {
    const float* x    = (const float*)d_in[0];
    const int*   ei   = (const int*)  d_in[1];
    const float* w_in = (const float*)d_in[2];
    const float* b_in = (const float*)d_in[3];
    const float* g1   = (const float*)d_in[4];
    const float* be1  = (const float*)d_in[5];
    const float* W1   = (const float*)d_in[6];
    const float* as1  = (const float*)d_in[7];
    const float* ad1  = (const float*)d_in[8];
    const float* bg1  = (const float*)d_in[9];
    const float* g2   = (const float*)d_in[10];
    const float* be2  = (const float*)d_in[11];
    const float* W2   = (const float*)d_in[12];
    const float* as2  = (const float*)d_in[13];
    const float* ad2  = (const float*)d_in[14];
    const float* bg2  = (const float*)d_in[15];
    const float* w_o  = (const float*)d_in[16];
    const float* b_o  = (const float*)d_in[17];
    float* out = (float*)d_out;

    char* p = (char*)d_ws;
    auto take = [&](size_t bytes) {
        void* r = p;
        p += (bytes + 255) & ~(size_t)255;
        return r;
    };
    float*  gout  = (float*)take((size_t)NN * HID * 4);
    float*  h2    = (float*)take((size_t)NN * HID * 4);
    ushort* hWb   = (ushort*)take((size_t)NN * HID * 2);
    float*  esrc  = (float*)take((size_t)NN * 4 * 4);
    float*  edst  = (float*)take((size_t)NN * 4 * 4);
    int*    off   = (int*)take((size_t)(NN + 1) * 4);
    int*    csr   = (int*)take((size_t)ETOT * 4);
    int*    dstid = (int*)take((size_t)ETOT * 4);
    size_t ovl = (size_t)ETOT * 8;
    size_t tsz = (size_t)NBK * CAP * 4;
    ushort* wexp  = (ushort*)take(ovl > tsz ? ovl : tsz);
    int*    tmp   = (int*)wexp;
    int*    bcur  = (int*)take((size_t)NBK * 4);
    int*    bstart= (int*)take((size_t)NBK * 4);
    ushort* Bp1   = (ushort*)take((size_t)1024 * 16);  // w_in frags: 8 tiles x 2 ksteps
    ushort* BpW1  = (ushort*)take((size_t)2048 * 16);  // W1 frags: 8 x 4
    ushort* BpW2  = (ushort*)take((size_t)2048 * 16);  // W2 frags

    k_pack<<<4, 256, 0, stream>>>(w_in, Bp1, 64, 128);
    k_pack<<<8, 256, 0, stream>>>(W1, BpW1, 128, 128);
    k_pack<<<8, 256, 0, stream>>>(W2, BpW2, 128, 128);

    k_zero      <<<(NBK + 255) / 256, 256, 0, stream>>>(bcur);
    k_bucket    <<<BBLK, 1024, 0, stream>>>(ei, bcur, tmp);
    k_bscan     <<<1, NBK, 0, stream>>>(bcur, bstart, off);
    k_bucket2csr<<<NBK, 256, 0, stream>>>(tmp, bcur, bstart, off, csr, dstid);

    int gfeat = (NN + 31) / 32;
    k_infeat<<<gfeat, 128, 0, stream>>>(x, Bp1, b_in, g1, be1, BpW1, as1, ad1, hWb, esrc, edst);
    k_edgew <<<(ETOT + 255) / 256, 256, 0, stream>>>(csr, dstid, esrc, edst, wexp);
    k_gat   <<<NN, 128, 0, stream>>>(hWb, wexp, off, csr, bg1, gout);
    k_feat  <<<gfeat, 128, 0, stream>>>(gout, g2, be2, BpW2, as2, ad2, hWb, esrc, edst);
    k_edgew <<<(ETOT + 255) / 256, 256, 0, stream>>>(csr, dstid, esrc, edst, wexp);
    k_gat   <<<NN, 128, 0, stream>>>(hWb, wexp, off, csr, bg2, h2);
    k_out   <<<NN / 16, 64, 0, stream>>>(h2, w_o, b_o, out);
}